// Round 8
// baseline (74174.072 us; speedup 1.0000x reference)
//
#include <hip/hip_runtime.h>

#define TT 2048
#define FF 64
#define HH 256

typedef short short8 __attribute__((ext_vector_type(8)));
typedef float f32x4 __attribute__((ext_vector_type(4)));
typedef unsigned long long u64t;
typedef unsigned u32t;

// ws layout (bytes):
//  [0)        packed bf16 weights: WhhE@0 WihE@262144 WhhD@327680 WihD@589824 WoutP@655360 (ushort idx)
//  [1343488)  hbL2 : [2 par][8 bb][256 U][8 rp] u64 tagged h-words (fast, XCD-L2 scope) 262144 B
//  [1605632)  hbDev: same layout, device-scope mirror                                    262144 B
#define WS_HB_B  1343488
#define WS_HBD_B 1605632

__device__ inline unsigned short f2b(float f) {
  unsigned int u = __builtin_bit_cast(unsigned int, f);
  u += 0x7fffu + ((u >> 16) & 1u);
  return (unsigned short)(u >> 16);
}
__device__ inline void pina(short8 &v) { asm volatile("" : "+a"(v)); }

// pack fragment-linear bf16 weights into ws
__global__ void prep_kernel(const float* __restrict__ Wih_e, const float* __restrict__ Whh_e,
                            const float* __restrict__ Wih_d, const float* __restrict__ Whh_d,
                            const float* __restrict__ Wout, unsigned short* __restrict__ ws) {
  int idx = blockIdx.x * blockDim.x + threadIdx.x;
  if (idx >= 83968) return;
  const float* src; unsigned short* dst; int q, kdim;
  if (idx < 32768)      { q = idx;         src = Whh_e; dst = ws + 0      + q * 8; kdim = HH; }
  else if (idx < 40960) { q = idx - 32768; src = Wih_e; dst = ws + 262144 + q * 8; kdim = FF; }
  else if (idx < 73728) { q = idx - 40960; src = Whh_d; dst = ws + 327680 + q * 8; kdim = HH; }
  else if (idx < 81920) { q = idx - 73728; src = Wih_d; dst = ws + 589824 + q * 8; kdim = FF; }
  else                  { q = idx - 81920; src = Wout;  dst = ws + 655360 + q * 8; kdim = HH; }
  int ksPerTile = (kdim == HH) ? 8 : 2;
  int per = ksPerTile * 64;
  int tile = q / per, rem = q % per;
  int ks = rem / 64, l = rem % 64;
  int col = tile * 16 + (l & 15);
  int k0 = ks * 32 + (l >> 4) * 8;
#pragma unroll
  for (int e = 0; e < 8; e++) dst[e] = f2b(src[col * kdim + k0 + e]);
}

// 32 blocks x 256 threads (4 waves). bb = bid&7 (batch group, peers share XCD under %8
// round-robin), gg = bid>>3 (hidden quarter). Wave w owns ALL 4 gates for units
// [64gg+16w, +16): 40 resident short8 per lane in AGPRs. Activation is wave-local.
// h exchange: tagged u64 words, sc0 stores/polls through the shared XCD L2; sc1 mirror fallback.
__global__ __launch_bounds__(256, 1) void lstm_kernel(
    const float* __restrict__ xg, const float* __restrict__ b_e,
    const float* __restrict__ b_d, const float* __restrict__ bout,
    const unsigned short* __restrict__ wsu, float* __restrict__ out,
    u64t* __restrict__ hbF, u64t* __restrict__ hbD) {
  __shared__ unsigned short zb[16][328];     // z = [h(256)|x(64)] bf16
  __shared__ unsigned short wout_lds[4096];  // Wout tile gg: [8 ks][64 lanes][8]

  const int tid = threadIdx.x;
  const int l = tid & 63, w = tid >> 6;      // 4 waves
  const int ln = l & 15, lk = l >> 4;
  const int bb = blockIdx.x & 7, gg = blockIdx.x >> 3;
  const int b0 = bb * 16;

  { const short8* WoutP = (const short8*)(wsu + 655360);
    ((short8*)wout_lds)[tid] = WoutP[gg * 512 + tid];
    ((short8*)wout_lds)[tid + 256] = WoutP[gg * 512 + tid + 256]; }

  const float bo_ = bout[16 * gg + ln];
  const int U = 64 * gg + 16 * w + ln;       // this lane's global hidden unit

  // consumer tables: 6 words/thread, m = k*256+tid over 192 peer units x 8 row-pairs
  int cidx[6], crow[6], cU[6];
#pragma unroll
  for (int k = 0; k < 6; k++) {
    int m = k * 256 + tid;
    int pu = m >> 3, rp = m & 7;
    int Up = pu + (pu >= 64 * gg ? 64 : 0);
    cidx[k] = (bb * 256 + Up) * 8 + rp;
    crow[k] = 2 * rp;
    cU[k] = Up;
  }
  const int pbase = (bb * 256 + U) * 8 + lk * 2;  // producer word base (2 words)

  float creg[4] = {0.f, 0.f, 0.f, 0.f};
  u32t hr0 = 0, hr1 = 0;  // own h pairs (rows lk*4+0/1 and +2/3)

  const int xrow = tid >> 4, xf = (tid & 15) * 4;
  const float* xrp = xg + (size_t)(b0 + xrow) * TT * FF + xf;
  float4 xv = *(const float4*)xrp;  // t = 0

  __syncthreads();  // wout_lds visible

  for (int ph = 0; ph < 2; ++ph) {
    const short8* WhhP = (const short8*)(wsu + (ph ? 327680 : 0));
    const short8* WihP = (const short8*)(wsu + (ph ? 589824 : 262144));
    const float* bias = ph ? b_d : b_e;

    // resident weights: all 4 gates x 10 ks for this lane's 16-unit tile (160 regs -> AGPR)
    short8 rW0[10], rW1[10], rW2[10], rW3[10];
#pragma unroll
    for (int ks = 0; ks < 8; ks++) {
      rW0[ks] = WhhP[((0 * 16 + 4 * gg + w) * 8 + ks) * 64 + l];
      rW1[ks] = WhhP[((1 * 16 + 4 * gg + w) * 8 + ks) * 64 + l];
      rW2[ks] = WhhP[((2 * 16 + 4 * gg + w) * 8 + ks) * 64 + l];
      rW3[ks] = WhhP[((3 * 16 + 4 * gg + w) * 8 + ks) * 64 + l];
    }
#pragma unroll
    for (int j = 0; j < 2; j++) {
      rW0[8 + j] = WihP[((0 * 16 + 4 * gg + w) * 2 + j) * 64 + l];
      rW1[8 + j] = WihP[((1 * 16 + 4 * gg + w) * 2 + j) * 64 + l];
      rW2[8 + j] = WihP[((2 * 16 + 4 * gg + w) * 2 + j) * 64 + l];
      rW3[8 + j] = WihP[((3 * 16 + 4 * gg + w) * 2 + j) * 64 + l];
    }
    float bact[4];
#pragma unroll
    for (int g = 0; g < 4; g++) bact[g] = bias[g * 256 + U];

#pragma unroll 1
    for (int ti = 0; ti < TT; ++ti) {
      const int it = ph * TT + ti;
      const int t = ph ? (TT - 1 - ti) : ti;

      // keep resident weights pinned in AGPRs every iteration (no remat possible)
#pragma unroll
      for (int ks = 0; ks < 10; ks++) { pina(rW0[ks]); pina(rW1[ks]); pina(rW2[ks]); pina(rW3[ks]); }

      // stage x(t)
      *(u32t*)&zb[xrow][HH + xf]     = (u32t)f2b(xv.x) | ((u32t)f2b(xv.y) << 16);
      *(u32t*)&zb[xrow][HH + xf + 2] = (u32t)f2b(xv.z) | ((u32t)f2b(xv.w) << 16);

      if (it == 0) {  // h(0) = 0, no exchange
#pragma unroll
        for (int i = 0; i < 8; i++) {
          int q = i * 256 + tid;            // 2048 u32 covering zb[:][0..255]
          *(u32t*)&zb[q >> 7][(q & 127) * 2] = 0u;
        }
      } else {
        // stage own h
        zb[lk * 4 + 0][U] = (unsigned short)hr0;
        zb[lk * 4 + 1][U] = (unsigned short)(hr0 >> 16);
        zb[lk * 4 + 2][U] = (unsigned short)hr1;
        zb[lk * 4 + 3][U] = (unsigned short)(hr1 >> 16);

        // spin on 6 peer words: fast = sc0 (shared XCD L2); fallback = sc0 sc1 mirror
        const u64t* bF = hbF + (size_t)(it & 1) * 16384;
        const u64t* bS = hbD + (size_t)(it & 1) * 16384;
        u64t v0 = 0, v1 = 0, v2 = 0, v3 = 0, v4 = 0, v5 = 0;
        bool d0 = false, d1 = false, d2 = false, d3 = false, d4 = false, d5 = false;
        int spins = 0;
        for (;;) {
          u64t t0, t1, t2, t3, t4, t5;
          asm volatile(
              "global_load_dwordx2 %0, %6, off sc0\n\t"
              "global_load_dwordx2 %1, %7, off sc0\n\t"
              "global_load_dwordx2 %2, %8, off sc0\n\t"
              "global_load_dwordx2 %3, %9, off sc0\n\t"
              "global_load_dwordx2 %4, %10, off sc0\n\t"
              "global_load_dwordx2 %5, %11, off sc0\n\t"
              "s_waitcnt vmcnt(0)"
              : "=&v"(t0), "=&v"(t1), "=&v"(t2), "=&v"(t3), "=&v"(t4), "=&v"(t5)
              : "v"(bF + cidx[0]), "v"(bF + cidx[1]), "v"(bF + cidx[2]),
                "v"(bF + cidx[3]), "v"(bF + cidx[4]), "v"(bF + cidx[5])
              : "memory");
          if (!d0 && (u32t)t0 == (u32t)it) { v0 = t0; d0 = true; }
          if (!d1 && (u32t)t1 == (u32t)it) { v1 = t1; d1 = true; }
          if (!d2 && (u32t)t2 == (u32t)it) { v2 = t2; d2 = true; }
          if (!d3 && (u32t)t3 == (u32t)it) { v3 = t3; d3 = true; }
          if (!d4 && (u32t)t4 == (u32t)it) { v4 = t4; d4 = true; }
          if (!d5 && (u32t)t5 == (u32t)it) { v5 = t5; d5 = true; }
          if (d0 && d1 && d2 && d3 && d4 && d5) break;
          if (((++spins) & 63) == 0) {  // device-scope fallback (cross-XCD liveness)
            u64t s0, s1, s2, s3, s4, s5;
            asm volatile(
                "global_load_dwordx2 %0, %6, off sc0 sc1\n\t"
                "global_load_dwordx2 %1, %7, off sc0 sc1\n\t"
                "global_load_dwordx2 %2, %8, off sc0 sc1\n\t"
                "global_load_dwordx2 %3, %9, off sc0 sc1\n\t"
                "global_load_dwordx2 %4, %10, off sc0 sc1\n\t"
                "global_load_dwordx2 %5, %11, off sc0 sc1\n\t"
                "s_waitcnt vmcnt(0)"
                : "=&v"(s0), "=&v"(s1), "=&v"(s2), "=&v"(s3), "=&v"(s4), "=&v"(s5)
                : "v"(bS + cidx[0]), "v"(bS + cidx[1]), "v"(bS + cidx[2]),
                  "v"(bS + cidx[3]), "v"(bS + cidx[4]), "v"(bS + cidx[5])
                : "memory");
            if (!d0 && (u32t)s0 == (u32t)it) { v0 = s0; d0 = true; }
            if (!d1 && (u32t)s1 == (u32t)it) { v1 = s1; d1 = true; }
            if (!d2 && (u32t)s2 == (u32t)it) { v2 = s2; d2 = true; }
            if (!d3 && (u32t)s3 == (u32t)it) { v3 = s3; d3 = true; }
            if (!d4 && (u32t)s4 == (u32t)it) { v4 = s4; d4 = true; }
            if (!d5 && (u32t)s5 == (u32t)it) { v5 = s5; d5 = true; }
            if (d0 && d1 && d2 && d3 && d4 && d5) break;
          }
        }
        // unpack peers into zb
        zb[crow[0]][cU[0]] = (unsigned short)(v0 >> 32); zb[crow[0] + 1][cU[0]] = (unsigned short)(v0 >> 48);
        zb[crow[1]][cU[1]] = (unsigned short)(v1 >> 32); zb[crow[1] + 1][cU[1]] = (unsigned short)(v1 >> 48);
        zb[crow[2]][cU[2]] = (unsigned short)(v2 >> 32); zb[crow[2] + 1][cU[2]] = (unsigned short)(v2 >> 48);
        zb[crow[3]][cU[3]] = (unsigned short)(v3 >> 32); zb[crow[3] + 1][cU[3]] = (unsigned short)(v3 >> 48);
        zb[crow[4]][cU[4]] = (unsigned short)(v4 >> 32); zb[crow[4] + 1][cU[4]] = (unsigned short)(v4 >> 48);
        zb[crow[5]][cU[5]] = (unsigned short)(v5 >> 32); zb[crow[5] + 1][cU[5]] = (unsigned short)(v5 >> 48);
      }
      __syncthreads();  // B1: full z assembled

      short8 afr[10];
#pragma unroll
      for (int ks = 0; ks < 10; ks++) afr[ks] = *(const short8*)&zb[ln][ks * 32 + lk * 8];
      __syncthreads();  // B2: all z reads done -> zb writable next step

      {  // prefetch next x
        int it2 = it + 1; if (it2 >= 2 * TT) it2 = 0;
        int t2 = (it2 < TT) ? it2 : (2 * TT - 1 - it2);
        xv = *(const float4*)(xrp + (size_t)t2 * FF);
      }

      f32x4 a0 = {0.f, 0.f, 0.f, 0.f}, a1 = {0.f, 0.f, 0.f, 0.f};
      f32x4 a2 = {0.f, 0.f, 0.f, 0.f}, a3 = {0.f, 0.f, 0.f, 0.f};
#pragma unroll
      for (int ks = 0; ks < 10; ks++) {
        a0 = __builtin_amdgcn_mfma_f32_16x16x32_bf16(afr[ks], rW0[ks], a0, 0, 0, 0);
        a1 = __builtin_amdgcn_mfma_f32_16x16x32_bf16(afr[ks], rW1[ks], a1, 0, 0, 0);
        a2 = __builtin_amdgcn_mfma_f32_16x16x32_bf16(afr[ks], rW2[ks], a2, 0, 0, 0);
        a3 = __builtin_amdgcn_mfma_f32_16x16x32_bf16(afr[ks], rW3[ks], a3, 0, 0, 0);
      }

      // decoder output, rotated across waves: out[:,t] = h(it) @ Wout^T + bout
      if (ph == 1 && w == (ti & 3)) {
        f32x4 oa = {0.f, 0.f, 0.f, 0.f};
#pragma unroll
        for (int ks = 0; ks < 8; ks++)
          oa = __builtin_amdgcn_mfma_f32_16x16x32_bf16(afr[ks], ((const short8*)wout_lds)[ks * 64 + l], oa, 0, 0, 0);
#pragma unroll
        for (int r = 0; r < 4; r++)
          out[((size_t)(b0 + lk * 4 + r) * TT + t) * FF + 16 * gg + ln] = oa[r] + bo_;
      }

      // wave-local activation: lane holds gates i,f,g,o for unit U, rows lk*4+r
      unsigned short hus[4];
#pragma unroll
      for (int r = 0; r < 4; r++) {
        float gi = a0[r] + bact[0];
        float gf = a1[r] + bact[1];
        float gG = a2[r] + bact[2];
        float go = a3[r] + bact[3];
        float si = 1.f / (1.f + __expf(-gi));
        float sf = 1.f / (1.f + __expf(-gf));
        float tg = 1.f - 2.f / (__expf(2.f * gG) + 1.f);
        float so = 1.f / (1.f + __expf(-go));
        float cn = sf * creg[r] + si * tg;
        creg[r] = cn;
        float hn = so * (1.f - 2.f / (__expf(2.f * cn) + 1.f));
        hus[r] = f2b(hn);
      }
      hr0 = (u32t)hus[0] | ((u32t)hus[1] << 16);
      hr1 = (u32t)hus[2] | ((u32t)hus[3] << 16);

      // publish h(it+1): fast sc0 words (XCD L2) + sc1 mirror (device) — fence-free
      {
        u64t wo0 = (u64t)(u32t)(it + 1) | ((u64t)hr0 << 32);
        u64t wo1 = (u64t)(u32t)(it + 1) | ((u64t)hr1 << 32);
        u64t* pF = hbF + (size_t)((it + 1) & 1) * 16384 + pbase;
        u64t* pS = hbD + (size_t)((it + 1) & 1) * 16384 + pbase;
        asm volatile(
            "global_store_dwordx2 %0, %1, off sc0\n\t"
            "global_store_dwordx2 %2, %3, off sc0\n\t"
            "global_store_dwordx2 %4, %1, off sc0 sc1\n\t"
            "global_store_dwordx2 %5, %3, off sc0 sc1"
            :: "v"(pF), "v"(wo0), "v"(pF + 1), "v"(wo1), "v"(pS), "v"(pS + 1)
            : "memory");
      }
    }
  }
}

extern "C" void kernel_launch(void* const* d_in, const int* in_sizes, int n_in,
                              void* d_out, int out_size, void* d_ws, size_t ws_size,
                              hipStream_t stream) {
  const float* ts    = (const float*)d_in[0];
  const float* Wih_e = (const float*)d_in[1];
  const float* Whh_e = (const float*)d_in[2];
  const float* b_e   = (const float*)d_in[3];
  const float* Wih_d = (const float*)d_in[4];
  const float* Whh_d = (const float*)d_in[5];
  const float* b_d   = (const float*)d_in[6];
  const float* Wout  = (const float*)d_in[7];
  const float* bout  = (const float*)d_in[8];
  unsigned short* ws = (unsigned short*)d_ws;
  float* out = (float*)d_out;
  u64t* hbF = (u64t*)((char*)d_ws + WS_HB_B);
  u64t* hbD = (u64t*)((char*)d_ws + WS_HBD_B);

  prep_kernel<<<328, 256, 0, stream>>>(Wih_e, Whh_e, Wih_d, Whh_d, Wout, ws);
  lstm_kernel<<<32, 256, 0, stream>>>(ts, b_e, b_d, bout, ws, out, hbF, hbD);
}

// Round 9
// 18069.695 us; speedup vs baseline: 4.1049x; 4.1049x over previous
//
#include <hip/hip_runtime.h>

#define TT 2048
#define FF 64
#define HH 256
#define ZSTR 344  // zb row stride in ushorts (688B: <=4-way bank aliasing, 16B aligned)

typedef short short8 __attribute__((ext_vector_type(8)));
typedef float f32x4 __attribute__((ext_vector_type(4)));
typedef unsigned long long u64t;
typedef unsigned u32t;

// ws layout (bytes):
//  [0)        packed bf16 weights: WhhE@0 WihE@262144 WhhD@327680 WihD@589824 WoutP@655360 (ushort idx)
//  [1343488)  hb: [2 par][8 bb][256 U][8 rp] u64 tagged h-words = 32768*8 = 262144 B
#define WS_HB_B 1343488

__device__ inline unsigned short f2b(float f) {
  unsigned int u = __builtin_bit_cast(unsigned int, f);
  u += 0x7fffu + ((u >> 16) & 1u);
  return (unsigned short)(u >> 16);
}
__device__ inline void pina(short8 &v) { asm volatile("" : "+a"(v)); }

// pack fragment-linear bf16 weights into ws (unchanged)
__global__ void prep_kernel(const float* __restrict__ Wih_e, const float* __restrict__ Whh_e,
                            const float* __restrict__ Wih_d, const float* __restrict__ Whh_d,
                            const float* __restrict__ Wout, unsigned short* __restrict__ ws) {
  int idx = blockIdx.x * blockDim.x + threadIdx.x;
  if (idx >= 83968) return;
  const float* src; unsigned short* dst; int q, kdim;
  if (idx < 32768)      { q = idx;         src = Whh_e; dst = ws + 0      + q * 8; kdim = HH; }
  else if (idx < 40960) { q = idx - 32768; src = Wih_e; dst = ws + 262144 + q * 8; kdim = FF; }
  else if (idx < 73728) { q = idx - 40960; src = Whh_d; dst = ws + 327680 + q * 8; kdim = HH; }
  else if (idx < 81920) { q = idx - 73728; src = Wih_d; dst = ws + 589824 + q * 8; kdim = FF; }
  else                  { q = idx - 81920; src = Wout;  dst = ws + 655360 + q * 8; kdim = HH; }
  int ksPerTile = (kdim == HH) ? 8 : 2;
  int per = ksPerTile * 64;
  int tile = q / per, rem = q % per;
  int ks = rem / 64, l = rem % 64;
  int col = tile * 16 + (l & 15);
  int k0 = ks * 32 + (l >> 4) * 8;
#pragma unroll
  for (int e = 0; e < 8; e++) dst[e] = f2b(src[col * kdim + k0 + e]);
}

// zero tagged exchange buffer each launch (tag 0 matches no polled step)
__global__ void init_hb(u64t* __restrict__ hb) {
  int i = blockIdx.x * blockDim.x + threadIdx.x;
  if (i < 32768) hb[i] = 0ull;
}

// 16 blocks x 256 threads (4 waves). bb = bid>>1 (batch group), gg = bid&1 (hidden half, 128 units).
// Whh register-resident in AGPRs (pinned every iter); Wih + Wout in LDS. Own-half MFMA issued
// BEFORE the peer spin (overlaps MALL RTT). Fence-free tagged u64 agent-scope exchange (r7-proven).
__global__ __launch_bounds__(256, 1) void lstm_kernel(
    const float* __restrict__ xg, const float* __restrict__ b_e,
    const float* __restrict__ b_d, const float* __restrict__ bout,
    const unsigned short* __restrict__ wsu, float* __restrict__ out,
    u64t* __restrict__ hb) {
  extern __shared__ unsigned short smem[];
  // smem: zb[2][16][ZSTR] @0 (11008), wout[2 tiles][8 ks][64][8] @11008 (8192),
  //       wih[32 tiles][2 j][64][8] @19200 (32768)  -> 51968 ushorts = 103936 B
  unsigned short* zbb = smem;
  unsigned short* wout_lds = smem + 11008;
  unsigned short* wih_lds = smem + 19200;

  const int tid = threadIdx.x;
  const int l = tid & 63, w = tid >> 6;      // 4 waves
  const int ln = l & 15, lk = l >> 4;
  const int bb = blockIdx.x >> 1, gg = blockIdx.x & 1;
  const int b0 = bb * 16;
  const int KO = 4 * gg, KP = 4 * (1 - gg);  // own / peer ks slice bases

  {  // stage Wout tiles 2gg, 2gg+1 (once)
    const short8* WoutP = (const short8*)(wsu + 655360);
    short8* wl = (short8*)wout_lds;
#pragma unroll
    for (int k = 0; k < 4; k++) wl[tid + 256 * k] = WoutP[gg * 1024 + tid + 256 * k];
  }
  const float bo0 = bout[32 * gg + ln], bo1 = bout[32 * gg + 16 + ln];

  // consumer tables: 4 words/thread over peer 128 units x 8 row-pairs
  int cidx[4], crow[4], cU[4];
#pragma unroll
  for (int k = 0; k < 4; k++) {
    int m = k * 256 + tid;
    int pu = m >> 3, rp = m & 7;
    int Up = 128 * (1 - gg) + pu;
    cidx[k] = (bb * 256 + Up) * 8 + rp;
    crow[k] = 2 * rp;
    cU[k] = Up;
  }
  // producer: units U0 (s=0), U0+16 (s=1), rows 4lk..4lk+3 -> word pairs
  const int U0 = 128 * gg + 32 * w + ln;
  const int p0 = (bb * 256 + U0) * 8 + 2 * lk;
  const int p1 = (bb * 256 + U0 + 16) * 8 + 2 * lk;

  float creg[2][4];
#pragma unroll
  for (int s = 0; s < 2; s++)
#pragma unroll
    for (int r = 0; r < 4; r++) creg[s][r] = 0.f;

  const int xrow = tid >> 4, xf = (tid & 15) * 4;
  const float* xrp = xg + (size_t)(b0 + xrow) * TT * FF + xf;
  float4 xv = *(const float4*)xrp;  // x(t=0)

  // prologue: zero zb[0] h region, stage x(0) into zb[0], prefetch x(1)
#pragma unroll
  for (int i = 0; i < 8; i++) {
    int q = i * 256 + tid;  // 2048 u32 cover cols 0..255 of 16 rows
    *(u32t*)&zbb[(q >> 7) * ZSTR + (q & 127) * 2] = 0u;
  }
  *(u32t*)&zbb[xrow * ZSTR + HH + xf]     = (u32t)f2b(xv.x) | ((u32t)f2b(xv.y) << 16);
  *(u32t*)&zbb[xrow * ZSTR + HH + xf + 2] = (u32t)f2b(xv.z) | ((u32t)f2b(xv.w) << 16);
  xv = *(const float4*)(xrp + FF);  // x(1)

  for (int ph = 0; ph < 2; ++ph) {
    const short8* WhhP = (const short8*)(wsu + (ph ? 327680 : 0));
    const short8* WihP = (const short8*)(wsu + (ph ? 589824 : 262144));
    const float* bias = ph ? b_d : b_e;

    {  // stage this block's 32 Wih tiles (x2 ks) into LDS
      short8* wl = (short8*)wih_lds;
#pragma unroll
      for (int k = 0; k < 16; k++) {
        int i = tid + 256 * k;
        int li = i & 63, jj = (i >> 6) & 1, sub = (i >> 7) & 7, g = i >> 10;
        wl[i] = WihP[((g * 16 + 8 * gg + sub) * 2 + jj) * 64 + li];
      }
    }

    // register-resident Whh: 8 tiles x 8 ks, split by own/peer k-halves (64 short8 -> AGPR)
    short8 rOwn[4][2][4], rPeer[4][2][4];
#pragma unroll
    for (int g = 0; g < 4; g++)
#pragma unroll
      for (int s = 0; s < 2; s++) {
        int c = g * 16 + 8 * gg + 2 * w + s;
#pragma unroll
        for (int j = 0; j < 4; j++) {
          rOwn[g][s][j]  = WhhP[(c * 8 + KO + j) * 64 + l];
          rPeer[g][s][j] = WhhP[(c * 8 + KP + j) * 64 + l];
        }
      }

    float bact[4][2];
#pragma unroll
    for (int g = 0; g < 4; g++) {
      bact[g][0] = bias[g * 256 + U0];
      bact[g][1] = bias[g * 256 + U0 + 16];
    }

    __syncthreads();  // wih staged (and prologue zb for ph 0) visible

#pragma unroll 1
    for (int ti = 0; ti < TT; ++ti) {
      const int it = ph * TT + ti;
      const int t = ph ? (TT - 1 - ti) : ti;
      unsigned short* zc = zbb + (it & 1) * (16 * ZSTR);
      unsigned short* zn = zbb + ((it & 1) ^ 1) * (16 * ZSTR);

      // pin resident Whh in AGPRs every iteration (remat impossible)
#pragma unroll
      for (int g = 0; g < 4; g++)
#pragma unroll
        for (int s = 0; s < 2; s++)
#pragma unroll
          for (int j = 0; j < 4; j++) { pina(rOwn[g][s][j]); pina(rPeer[g][s][j]); }

      // own-half + x fragments (staged last step; B2 ordered)
      short8 aOwn[4], aX[2];
#pragma unroll
      for (int j = 0; j < 4; j++) aOwn[j] = *(const short8*)&zc[ln * ZSTR + (KO + j) * 32 + lk * 8];
#pragma unroll
      for (int j = 0; j < 2; j++) aX[j] = *(const short8*)&zc[ln * ZSTR + (8 + j) * 32 + lk * 8];

      f32x4 acc[4][2];
#pragma unroll
      for (int g = 0; g < 4; g++)
#pragma unroll
        for (int s = 0; s < 2; s++) acc[g][s] = f32x4{0.f, 0.f, 0.f, 0.f};

      // 48 MFMA on own+x data BEFORE the peer wait (overlaps MALL RTT)
#pragma unroll
      for (int j = 0; j < 4; j++)
#pragma unroll
        for (int g = 0; g < 4; g++)
#pragma unroll
          for (int s = 0; s < 2; s++)
            acc[g][s] = __builtin_amdgcn_mfma_f32_16x16x32_bf16(aOwn[j], rOwn[g][s][j], acc[g][s], 0, 0, 0);
#pragma unroll
      for (int j = 0; j < 2; j++)
#pragma unroll
        for (int g = 0; g < 4; g++)
#pragma unroll
          for (int s = 0; s < 2; s++) {
            short8 bf = ((const short8*)wih_lds)[((g * 8 + 2 * w + s) * 2 + j) * 64 + l];
            acc[g][s] = __builtin_amdgcn_mfma_f32_16x16x32_bf16(aX[j], bf, acc[g][s], 0, 0, 0);
          }

      // spin on 4 peer words (fence-free tagged, agent scope — r7-proven), unpack into zc
      if (it) {
        const u64t* base = hb + (size_t)(it & 1) * 16384;
        u64t v0 = 0, v1 = 0, v2 = 0, v3 = 0;
        bool d0 = false, d1 = false, d2 = false, d3 = false;
        do {
          if (!d0) { v0 = __hip_atomic_load(base + cidx[0], __ATOMIC_RELAXED, __HIP_MEMORY_SCOPE_AGENT);
                     d0 = ((u32t)v0 == (u32t)it); }
          if (!d1) { v1 = __hip_atomic_load(base + cidx[1], __ATOMIC_RELAXED, __HIP_MEMORY_SCOPE_AGENT);
                     d1 = ((u32t)v1 == (u32t)it); }
          if (!d2) { v2 = __hip_atomic_load(base + cidx[2], __ATOMIC_RELAXED, __HIP_MEMORY_SCOPE_AGENT);
                     d2 = ((u32t)v2 == (u32t)it); }
          if (!d3) { v3 = __hip_atomic_load(base + cidx[3], __ATOMIC_RELAXED, __HIP_MEMORY_SCOPE_AGENT);
                     d3 = ((u32t)v3 == (u32t)it); }
        } while (!(d0 && d1 && d2 && d3));
        zc[crow[0] * ZSTR + cU[0]] = (unsigned short)(v0 >> 32);
        zc[(crow[0] + 1) * ZSTR + cU[0]] = (unsigned short)(v0 >> 48);
        zc[crow[1] * ZSTR + cU[1]] = (unsigned short)(v1 >> 32);
        zc[(crow[1] + 1) * ZSTR + cU[1]] = (unsigned short)(v1 >> 48);
        zc[crow[2] * ZSTR + cU[2]] = (unsigned short)(v2 >> 32);
        zc[(crow[2] + 1) * ZSTR + cU[2]] = (unsigned short)(v2 >> 48);
        zc[crow[3] * ZSTR + cU[3]] = (unsigned short)(v3 >> 32);
        zc[(crow[3] + 1) * ZSTR + cU[3]] = (unsigned short)(v3 >> 48);
      }
      __syncthreads();  // B1: peer half of z visible

      short8 aPeer[4];
#pragma unroll
      for (int j = 0; j < 4; j++) aPeer[j] = *(const short8*)&zc[ln * ZSTR + (KP + j) * 32 + lk * 8];
#pragma unroll
      for (int j = 0; j < 4; j++)
#pragma unroll
        for (int g = 0; g < 4; g++)
#pragma unroll
          for (int s = 0; s < 2; s++)
            acc[g][s] = __builtin_amdgcn_mfma_f32_16x16x32_bf16(aPeer[j], rPeer[g][s][j], acc[g][s], 0, 0, 0);

      // wave-local activation (lane: units U0, U0+16; rows 4lk..+3), then publish
      u32t h01[2], h23[2];
#pragma unroll
      for (int s = 0; s < 2; s++) {
        unsigned short hu[4];
#pragma unroll
        for (int r = 0; r < 4; r++) {
          float gi = acc[0][s][r] + bact[0][s];
          float gf = acc[1][s][r] + bact[1][s];
          float gG = acc[2][s][r] + bact[2][s];
          float go = acc[3][s][r] + bact[3][s];
          float si = 1.f / (1.f + __expf(-gi));
          float sf = 1.f / (1.f + __expf(-gf));
          float tg = 1.f - 2.f / (__expf(2.f * gG) + 1.f);
          float so = 1.f / (1.f + __expf(-go));
          float cn = sf * creg[s][r] + si * tg;
          creg[s][r] = cn;
          float hn = so * (1.f - 2.f / (__expf(2.f * cn) + 1.f));
          hu[r] = f2b(hn);
        }
        h01[s] = (u32t)hu[0] | ((u32t)hu[1] << 16);
        h23[s] = (u32t)hu[2] | ((u32t)hu[3] << 16);
      }
      {  // publish h(it+1): tagged u64 words, relaxed agent atomics (no fence)
        u64t* bp = hb + (size_t)((it + 1) & 1) * 16384;
        const u64t tag = (u64t)(u32t)(it + 1);
        __hip_atomic_store(bp + p0,     tag | ((u64t)h01[0] << 32), __ATOMIC_RELAXED, __HIP_MEMORY_SCOPE_AGENT);
        __hip_atomic_store(bp + p0 + 1, tag | ((u64t)h23[0] << 32), __ATOMIC_RELAXED, __HIP_MEMORY_SCOPE_AGENT);
        __hip_atomic_store(bp + p1,     tag | ((u64t)h01[1] << 32), __ATOMIC_RELAXED, __HIP_MEMORY_SCOPE_AGENT);
        __hip_atomic_store(bp + p1 + 1, tag | ((u64t)h23[1] << 32), __ATOMIC_RELAXED, __HIP_MEMORY_SCOPE_AGENT);
      }

      // stage own h(it+1) into next zb
      zn[(4 * lk + 0) * ZSTR + U0] = (unsigned short)h01[0];
      zn[(4 * lk + 1) * ZSTR + U0] = (unsigned short)(h01[0] >> 16);
      zn[(4 * lk + 2) * ZSTR + U0] = (unsigned short)h23[0];
      zn[(4 * lk + 3) * ZSTR + U0] = (unsigned short)(h23[0] >> 16);
      zn[(4 * lk + 0) * ZSTR + U0 + 16] = (unsigned short)h01[1];
      zn[(4 * lk + 1) * ZSTR + U0 + 16] = (unsigned short)(h01[1] >> 16);
      zn[(4 * lk + 2) * ZSTR + U0 + 16] = (unsigned short)h23[1];
      zn[(4 * lk + 3) * ZSTR + U0 + 16] = (unsigned short)(h23[1] >> 16);

      // decoder output (rotating wave, off critical path): out[:,t] = h(it) @ Wout^T + bout
      if (ph == 1 && w == (ti & 3)) {
        const short8* wl = (const short8*)wout_lds;
        f32x4 oa0 = {0.f, 0.f, 0.f, 0.f}, oa1 = {0.f, 0.f, 0.f, 0.f};
#pragma unroll
        for (int j = 0; j < 4; j++) {
          oa0 = __builtin_amdgcn_mfma_f32_16x16x32_bf16(aOwn[j], wl[(KO + j) * 64 + l], oa0, 0, 0, 0);
          oa1 = __builtin_amdgcn_mfma_f32_16x16x32_bf16(aOwn[j], wl[(8 + KO + j) * 64 + l], oa1, 0, 0, 0);
          oa0 = __builtin_amdgcn_mfma_f32_16x16x32_bf16(aPeer[j], wl[(KP + j) * 64 + l], oa0, 0, 0, 0);
          oa1 = __builtin_amdgcn_mfma_f32_16x16x32_bf16(aPeer[j], wl[(8 + KP + j) * 64 + l], oa1, 0, 0, 0);
        }
#pragma unroll
        for (int r = 0; r < 4; r++) {
          size_t o = ((size_t)(b0 + 4 * lk + r) * TT + t) * FF + 32 * gg;
          out[o + ln] = oa0[r] + bo0;
          out[o + 16 + ln] = oa1[r] + bo1;
        }
      }

      // stage x(t+1) into next zb; prefetch x(t+2)
      *(u32t*)&zn[xrow * ZSTR + HH + xf]     = (u32t)f2b(xv.x) | ((u32t)f2b(xv.y) << 16);
      *(u32t*)&zn[xrow * ZSTR + HH + xf + 2] = (u32t)f2b(xv.z) | ((u32t)f2b(xv.w) << 16);
      {
        int it2 = it + 2; if (it2 >= 2 * TT) it2 = 0;
        int t2 = (it2 < TT) ? it2 : (2 * TT - 1 - it2);
        xv = *(const float4*)(xrp + (size_t)t2 * FF);
      }
      __syncthreads();  // B2: next zb staged; zc reads done
    }
  }
}

extern "C" void kernel_launch(void* const* d_in, const int* in_sizes, int n_in,
                              void* d_out, int out_size, void* d_ws, size_t ws_size,
                              hipStream_t stream) {
  const float* ts    = (const float*)d_in[0];
  const float* Wih_e = (const float*)d_in[1];
  const float* Whh_e = (const float*)d_in[2];
  const float* b_e   = (const float*)d_in[3];
  const float* Wih_d = (const float*)d_in[4];
  const float* Whh_d = (const float*)d_in[5];
  const float* b_d   = (const float*)d_in[6];
  const float* Wout  = (const float*)d_in[7];
  const float* bout  = (const float*)d_in[8];
  unsigned short* ws = (unsigned short*)d_ws;
  float* out = (float*)d_out;
  u64t* hb = (u64t*)((char*)d_ws + WS_HB_B);

  const int ldsBytes = 51968 * 2;  // 103936 B
  (void)hipFuncSetAttribute((const void*)lstm_kernel,
                            hipFuncAttributeMaxDynamicSharedMemorySize, ldsBytes);

  prep_kernel<<<328, 256, 0, stream>>>(Wih_e, Whh_e, Wih_d, Whh_d, Wout, ws);
  init_hb<<<64, 512, 0, stream>>>(hb);
  lstm_kernel<<<16, 256, ldsBytes, stream>>>(ts, b_e, b_d, bout, ws, out, hb);
}

// Round 10
// 11768.079 us; speedup vs baseline: 6.3030x; 1.5355x over previous
//
#include <hip/hip_runtime.h>

#define TT 2048
#define FF 64
#define HH 256
#define ZSTR 344  // zb row stride (ushorts)

typedef short short8 __attribute__((ext_vector_type(8)));
typedef float f32x4 __attribute__((ext_vector_type(4)));
typedef unsigned long long u64t;
typedef unsigned u32t;

// ws layout (bytes):
//  [0)        packed bf16 weights: WhhE@0 WihE@262144 WhhD@327680 WihD@589824 WoutP@655360 (ushort idx)
//  [1343488)  hb: [2 par][8 bb][256 U][8 rp] u64 tagged h-words = 32768*8 = 262144 B
#define WS_HB_B 1343488

__device__ inline unsigned short f2b(float f) {
  unsigned int u = __builtin_bit_cast(unsigned int, f);
  u += 0x7fffu + ((u >> 16) & 1u);
  return (unsigned short)(u >> 16);
}

// pack fragment-linear bf16 weights into ws (unchanged)
__global__ void prep_kernel(const float* __restrict__ Wih_e, const float* __restrict__ Whh_e,
                            const float* __restrict__ Wih_d, const float* __restrict__ Whh_d,
                            const float* __restrict__ Wout, unsigned short* __restrict__ ws) {
  int idx = blockIdx.x * blockDim.x + threadIdx.x;
  if (idx >= 83968) return;
  const float* src; unsigned short* dst; int q, kdim;
  if (idx < 32768)      { q = idx;         src = Whh_e; dst = ws + 0      + q * 8; kdim = HH; }
  else if (idx < 40960) { q = idx - 32768; src = Wih_e; dst = ws + 262144 + q * 8; kdim = FF; }
  else if (idx < 73728) { q = idx - 40960; src = Whh_d; dst = ws + 327680 + q * 8; kdim = HH; }
  else if (idx < 81920) { q = idx - 73728; src = Wih_d; dst = ws + 589824 + q * 8; kdim = FF; }
  else                  { q = idx - 81920; src = Wout;  dst = ws + 655360 + q * 8; kdim = HH; }
  int ksPerTile = (kdim == HH) ? 8 : 2;
  int per = ksPerTile * 64;
  int tile = q / per, rem = q % per;
  int ks = rem / 64, l = rem % 64;
  int col = tile * 16 + (l & 15);
  int k0 = ks * 32 + (l >> 4) * 8;
#pragma unroll
  for (int e = 0; e < 8; e++) dst[e] = f2b(src[col * kdim + k0 + e]);
}

// zero tagged exchange buffer each launch
__global__ void init_hb(u64t* __restrict__ hb) {
  int i = blockIdx.x * blockDim.x + threadIdx.x;
  if (i < 32768) hb[i] = 0ull;
}

// 16 blocks x 512 threads (8 waves). bb = bid>>1 (batch group), gg = bid&1 (hidden half).
// Wave w owns ALL 4 gates for 16 units (U = 128gg+16w+ln). Own-half + x MFMAs issued
// BEFORE the single-peer spin; only peer-ks MFMAs + act behind the RTT.
// Exchange: r7-proven tagged u64 relaxed agent atomics, fence-free, double-buffered by parity.
__global__ __launch_bounds__(512, 2) void lstm_kernel(
    const float* __restrict__ xg, const float* __restrict__ b_e,
    const float* __restrict__ b_d, const float* __restrict__ bout,
    const unsigned short* __restrict__ wsu, float* __restrict__ out,
    u64t* __restrict__ hb) {
  extern __shared__ unsigned short smem[];
  // zb[2][16][ZSTR] @0 (11008) | wout[2 tiles][8 ks][64][8] @11008 (8192) | wih[32 t][2 j][64][8] @19200 (32768)
  unsigned short* zbb = smem;
  unsigned short* wout_lds = smem + 11008;
  unsigned short* wih_lds = smem + 19200;

  const int tid = threadIdx.x;
  const int l = tid & 63, w = tid >> 6;      // 8 waves
  const int ln = l & 15, lk = l >> 4;
  const int bb = blockIdx.x >> 1, gg = blockIdx.x & 1;
  const int b0 = bb * 16;
  const int KO = 4 * gg, KP = 4 * (1 - gg);  // own / peer ks slice bases

  {  // stage Wout tiles 2gg, 2gg+1 (once)
    const short8* WoutP = (const short8*)(wsu + 655360);
    short8* wl = (short8*)wout_lds;
    wl[tid] = WoutP[gg * 1024 + tid];
    wl[tid + 512] = WoutP[gg * 1024 + tid + 512];
  }
  const float bo0 = bout[32 * gg + ln], bo1 = bout[32 * gg + 16 + ln];

  const int U = 128 * gg + 16 * w + ln;      // this lane's hidden unit

  // consumer: 2 words (m = tid, tid+512) over peer 128 units x 8 row-pairs
  int cidx0, crow0, cU0, cidx1, crow1, cU1;
  {
    int m = tid, pu = m >> 3, rp = m & 7;
    cU0 = 128 * (1 - gg) + pu; cidx0 = (bb * 256 + cU0) * 8 + rp; crow0 = 2 * rp;
    m = tid + 512; pu = m >> 3; rp = m & 7;
    cU1 = 128 * (1 - gg) + pu; cidx1 = (bb * 256 + cU1) * 8 + rp; crow1 = 2 * rp;
  }
  const int p0 = (bb * 256 + U) * 8 + 2 * lk;  // producer words p0, p0+1

  float creg[4] = {0.f, 0.f, 0.f, 0.f};

  const int xrow = tid >> 5, xf = (tid & 31) * 2;
  const float* xrp = xg + (size_t)(b0 + xrow) * TT * FF + xf;
  float2 xv = *(const float2*)xrp;  // x(0)

  // prologue: zero zb[0] h region (2048 u32), stage x(0), prefetch x(1)
#pragma unroll
  for (int i = 0; i < 4; i++) {
    int q = i * 512 + tid;
    *(u32t*)&zbb[(q >> 7) * ZSTR + (q & 127) * 2] = 0u;
  }
  *(u32t*)&zbb[xrow * ZSTR + HH + xf] = (u32t)f2b(xv.x) | ((u32t)f2b(xv.y) << 16);
  xv = *(const float2*)(xrp + FF);

  for (int ph = 0; ph < 2; ++ph) {
    const short8* WhhP = (const short8*)(wsu + (ph ? 327680 : 0));
    const short8* WihP = (const short8*)(wsu + (ph ? 589824 : 262144));
    const float* bias = ph ? b_d : b_e;

    {  // stage this block's 32 Wih tiles x 2 ks into LDS
      short8* wl = (short8*)wih_lds;
#pragma unroll
      for (int k = 0; k < 8; k++) {
        int i = tid + 512 * k;
        int li = i & 63, jj = (i >> 6) & 1, sub = (i >> 7) & 7, g = i >> 10;
        wl[i] = WihP[((g * 16 + 8 * gg + sub) * 2 + jj) * 64 + li];
      }
    }

    // Whh for this wave's 4 gate-tiles (c = g*16 + 8gg + w), split own/peer k-halves
    short8 rOwn[4][4], rPeer[4][4];
#pragma unroll
    for (int g = 0; g < 4; g++) {
      const int c = g * 16 + 8 * gg + w;
#pragma unroll
      for (int j = 0; j < 4; j++) {
        rOwn[g][j]  = WhhP[(c * 8 + KO + j) * 64 + l];
        rPeer[g][j] = WhhP[(c * 8 + KP + j) * 64 + l];
      }
    }

    float bact[4];
#pragma unroll
    for (int g = 0; g < 4; g++) bact[g] = bias[g * 256 + U];

    __syncthreads();  // wih/wout staged (and prologue zb) visible

#pragma unroll 1
    for (int ti = 0; ti < TT; ++ti) {
      const int it = ph * TT + ti;
      const int t = ph ? (TT - 1 - ti) : ti;
      unsigned short* zc = zbb + (it & 1) * (16 * ZSTR);
      unsigned short* zn = zbb + ((it & 1) ^ 1) * (16 * ZSTR);

      // own-half + x fragments (staged last step, B2-ordered)
      short8 aOwn[4], aX[2];
#pragma unroll
      for (int j = 0; j < 4; j++) aOwn[j] = *(const short8*)&zc[ln * ZSTR + (KO + j) * 32 + lk * 8];
#pragma unroll
      for (int j = 0; j < 2; j++) aX[j] = *(const short8*)&zc[ln * ZSTR + (8 + j) * 32 + lk * 8];

      f32x4 acc[4];
#pragma unroll
      for (int g = 0; g < 4; g++) acc[g] = f32x4{0.f, 0.f, 0.f, 0.f};

      // 24 MFMA on own+x BEFORE the peer wait (overlaps exchange RTT)
#pragma unroll
      for (int j = 0; j < 4; j++)
#pragma unroll
        for (int g = 0; g < 4; g++)
          acc[g] = __builtin_amdgcn_mfma_f32_16x16x32_bf16(aOwn[j], rOwn[g][j], acc[g], 0, 0, 0);
#pragma unroll
      for (int j = 0; j < 2; j++)
#pragma unroll
        for (int g = 0; g < 4; g++) {
          short8 bf = ((const short8*)wih_lds)[((g * 8 + w) * 2 + j) * 64 + l];
          acc[g] = __builtin_amdgcn_mfma_f32_16x16x32_bf16(aX[j], bf, acc[g], 0, 0, 0);
        }

      // spin on 2 peer words (tagged, relaxed agent — r7-proven), unpack into zc
      if (it) {
        const u64t* base = hb + (size_t)(it & 1) * 16384;
        u64t v0 = 0, v1 = 0;
        bool d0 = false, d1 = false;
        do {
          if (!d0) { v0 = __hip_atomic_load(base + cidx0, __ATOMIC_RELAXED, __HIP_MEMORY_SCOPE_AGENT);
                     d0 = ((u32t)v0 == (u32t)it); }
          if (!d1) { v1 = __hip_atomic_load(base + cidx1, __ATOMIC_RELAXED, __HIP_MEMORY_SCOPE_AGENT);
                     d1 = ((u32t)v1 == (u32t)it); }
        } while (!(d0 && d1));
        zc[crow0 * ZSTR + cU0] = (unsigned short)(v0 >> 32);
        zc[(crow0 + 1) * ZSTR + cU0] = (unsigned short)(v0 >> 48);
        zc[crow1 * ZSTR + cU1] = (unsigned short)(v1 >> 32);
        zc[(crow1 + 1) * ZSTR + cU1] = (unsigned short)(v1 >> 48);
      }
      __syncthreads();  // B1: peer half of z visible

      short8 aPeer[4];
#pragma unroll
      for (int j = 0; j < 4; j++) aPeer[j] = *(const short8*)&zc[ln * ZSTR + (KP + j) * 32 + lk * 8];
#pragma unroll
      for (int j = 0; j < 4; j++)
#pragma unroll
        for (int g = 0; g < 4; g++)
          acc[g] = __builtin_amdgcn_mfma_f32_16x16x32_bf16(aPeer[j], rPeer[g][j], acc[g], 0, 0, 0);

      // wave-local activation: lane holds i,f,g,o for unit U, rows 4lk+r
      unsigned short hu[4];
#pragma unroll
      for (int r = 0; r < 4; r++) {
        float gi = acc[0][r] + bact[0];
        float gf = acc[1][r] + bact[1];
        float gG = acc[2][r] + bact[2];
        float go = acc[3][r] + bact[3];
        float si = 1.f / (1.f + __expf(-gi));
        float sf = 1.f / (1.f + __expf(-gf));
        float tg = 1.f - 2.f / (__expf(2.f * gG) + 1.f);
        float so = 1.f / (1.f + __expf(-go));
        float cn = sf * creg[r] + si * tg;
        creg[r] = cn;
        float hn = so * (1.f - 2.f / (__expf(2.f * cn) + 1.f));
        hu[r] = f2b(hn);
      }
      const u32t h01 = (u32t)hu[0] | ((u32t)hu[1] << 16);
      const u32t h23 = (u32t)hu[2] | ((u32t)hu[3] << 16);

      {  // publish h(it+1) FIRST (peers' critical path), relaxed agent, fence-free
        u64t* bp = hb + (size_t)((it + 1) & 1) * 16384;
        const u64t tag = (u64t)(u32t)(it + 1);
        __hip_atomic_store(bp + p0,     tag | ((u64t)h01 << 32), __ATOMIC_RELAXED, __HIP_MEMORY_SCOPE_AGENT);
        __hip_atomic_store(bp + p0 + 1, tag | ((u64t)h23 << 32), __ATOMIC_RELAXED, __HIP_MEMORY_SCOPE_AGENT);
      }

      // stage own h(it+1) into next zb
      zn[(4 * lk + 0) * ZSTR + U] = hu[0];
      zn[(4 * lk + 1) * ZSTR + U] = hu[1];
      zn[(4 * lk + 2) * ZSTR + U] = hu[2];
      zn[(4 * lk + 3) * ZSTR + U] = hu[3];

      // decoder output (rotating wave): out[:,t] = h(it) @ Wout^T + bout, feats 32gg..+32
      if (ph == 1 && w == (ti & 7)) {
        const short8* wl = (const short8*)wout_lds;
        f32x4 oa0 = {0.f, 0.f, 0.f, 0.f}, oa1 = {0.f, 0.f, 0.f, 0.f};
#pragma unroll
        for (int j = 0; j < 4; j++) {
          oa0 = __builtin_amdgcn_mfma_f32_16x16x32_bf16(aOwn[j], wl[(KO + j) * 64 + l], oa0, 0, 0, 0);
          oa1 = __builtin_amdgcn_mfma_f32_16x16x32_bf16(aOwn[j], wl[(8 + KO + j) * 64 + l], oa1, 0, 0, 0);
          oa0 = __builtin_amdgcn_mfma_f32_16x16x32_bf16(aPeer[j], wl[(KP + j) * 64 + l], oa0, 0, 0, 0);
          oa1 = __builtin_amdgcn_mfma_f32_16x16x32_bf16(aPeer[j], wl[(8 + KP + j) * 64 + l], oa1, 0, 0, 0);
        }
#pragma unroll
        for (int r = 0; r < 4; r++) {
          size_t o = ((size_t)(b0 + 4 * lk + r) * TT + t) * FF + 32 * gg;
          out[o + ln] = oa0[r] + bo0;
          out[o + 16 + ln] = oa1[r] + bo1;
        }
      }

      // stage x(t+1) into next zb; prefetch x(t+2)
      *(u32t*)&zn[xrow * ZSTR + HH + xf] = (u32t)f2b(xv.x) | ((u32t)f2b(xv.y) << 16);
      {
        int it2 = it + 2; if (it2 >= 2 * TT) it2 = 0;
        int t2 = (it2 < TT) ? it2 : (2 * TT - 1 - it2);
        xv = *(const float2*)(xrp + (size_t)t2 * FF);
      }
      __syncthreads();  // B2: next zb staged; zc reads done
    }
    __syncthreads();  // phase edge: all reads done before wih restage
  }
}

extern "C" void kernel_launch(void* const* d_in, const int* in_sizes, int n_in,
                              void* d_out, int out_size, void* d_ws, size_t ws_size,
                              hipStream_t stream) {
  const float* ts    = (const float*)d_in[0];
  const float* Wih_e = (const float*)d_in[1];
  const float* Whh_e = (const float*)d_in[2];
  const float* b_e   = (const float*)d_in[3];
  const float* Wih_d = (const float*)d_in[4];
  const float* Whh_d = (const float*)d_in[5];
  const float* b_d   = (const float*)d_in[6];
  const float* Wout  = (const float*)d_in[7];
  const float* bout  = (const float*)d_in[8];
  unsigned short* ws = (unsigned short*)d_ws;
  float* out = (float*)d_out;
  u64t* hb = (u64t*)((char*)d_ws + WS_HB_B);

  const int ldsBytes = 51968 * 2;  // 103936 B
  (void)hipFuncSetAttribute((const void*)lstm_kernel,
                            hipFuncAttributeMaxDynamicSharedMemorySize, ldsBytes);

  prep_kernel<<<328, 256, 0, stream>>>(Wih_e, Whh_e, Wih_d, Whh_d, Wout, ws);
  init_hb<<<64, 512, 0, stream>>>(hb);
  lstm_kernel<<<16, 512, ldsBytes, stream>>>(ts, b_e, b_d, bout, ws, out, hb);
}